// Round 1
// baseline (1767.872 us; speedup 1.0000x reference)
//
#include <hip/hip_runtime.h>
#include <math.h>

#define N_NODES 100000
#define H_DIM 64
#define G_GRAPHS 512
#define NEG_SLOPE 0.2f

// ---------------------------------------------------------------------------
// CSR build
// ---------------------------------------------------------------------------
__global__ void hist_kernel(const int* __restrict__ dst, int* __restrict__ counts, int E) {
    int e = blockIdx.x * blockDim.x + threadIdx.x;
    if (e < E) atomicAdd(&counts[dst[e]], 1);
}

__global__ __launch_bounds__(1024) void scan_kernel(const int* __restrict__ counts,
                                                    int* __restrict__ off, int n) {
    __shared__ int lsum[1024];
    int t = threadIdx.x;
    int chunk = (n + 1023) / 1024;
    int begin = t * chunk;
    int end = begin + chunk; if (end > n) end = n;
    int s = 0;
    for (int i = begin; i < end; ++i) s += counts[i];
    lsum[t] = s;
    __syncthreads();
    // Hillis-Steele inclusive scan over 1024 partials
    for (int d = 1; d < 1024; d <<= 1) {
        int v = 0;
        if (t >= d) v = lsum[t - d];
        __syncthreads();
        lsum[t] += v;
        __syncthreads();
    }
    int run = (t == 0) ? 0 : lsum[t - 1];
    for (int i = begin; i < end; ++i) {
        off[i] = run;
        run += counts[i];
    }
    if (t == 1023) off[n] = lsum[1023];
}

__global__ void scatter_kernel(const int* __restrict__ src, const int* __restrict__ dst,
                               const int* __restrict__ off, int* __restrict__ fill,
                               int* __restrict__ edge_src, int E) {
    int e = blockIdx.x * blockDim.x + threadIdx.x;
    if (e < E) {
        int d = dst[e];
        int pos = off[d] + atomicAdd(&fill[d], 1);
        edge_src[pos] = src[e];
    }
}

// ---------------------------------------------------------------------------
// Fused GEMM + attention logits: h = act @ W ; ls = h.a_s ; ld = h.a_d
// One wave per node; W staged in LDS; act row broadcast via shfl.
// ---------------------------------------------------------------------------
template <int FIN>
__global__ __launch_bounds__(256) void gemm_logits_kernel(
        const float* __restrict__ act, const float* __restrict__ W,
        const float* __restrict__ a_s, const float* __restrict__ a_d,
        float* __restrict__ h, float* __restrict__ ls, float* __restrict__ ld,
        int n) {
    __shared__ float Wl[FIN * 64];
    __shared__ float asl[64];
    __shared__ float adl[64];
    int t = threadIdx.x;
    for (int i = t; i < FIN * 64; i += 256) Wl[i] = W[i];
    if (t < 64) { asl[t] = a_s[t]; adl[t] = a_d[t]; }
    __syncthreads();

    int wave = t >> 6;
    int lane = t & 63;
    int node = blockIdx.x * 4 + wave;
    if (node >= n) return;

    float xr = (lane < FIN) ? act[node * FIN + lane] : 0.0f;
    float acc = 0.0f;
#pragma unroll
    for (int k = 0; k < FIN; ++k) {
        float a = __shfl(xr, k, 64);
        acc += a * Wl[k * 64 + lane];   // bank: lane%32 -> 2-way (free)
    }
    float vs = acc * asl[lane];
    float vd = acc * adl[lane];
#pragma unroll
    for (int d = 32; d >= 1; d >>= 1) {
        vs += __shfl_xor(vs, d, 64);
        vd += __shfl_xor(vd, d, 64);
    }
    h[node * 64 + lane] = acc;
    if (lane == 0) { ls[node] = vs; ld[node] = vd; }
}

// ---------------------------------------------------------------------------
// GAT aggregation with online softmax. One wave per node; lane = feature.
// Self-loop seeds the running max/sum. Output: elu(agg + bias).
// ---------------------------------------------------------------------------
__global__ __launch_bounds__(256) void gat_aggregate_kernel(
        const float* __restrict__ h, const float* __restrict__ ls,
        const float* __restrict__ ld, const int* __restrict__ off,
        const int* __restrict__ edge_src, const float* __restrict__ bias,
        float* __restrict__ hout, int n) {
    int t = threadIdx.x;
    int wave = t >> 6;
    int lane = t & 63;
    int node = blockIdx.x * 4 + wave;
    if (node >= n) return;

    float ldv = ld[node];
    // self edge (src = dst = node)
    float e0 = ls[node] + ldv;
    e0 = (e0 >= 0.0f) ? e0 : NEG_SLOPE * e0;
    float m = e0;
    float lsum = 1.0f;                      // exp(e0 - m) = 1
    float acc = h[node * 64 + lane];        // weight 1

    int jb = off[node];
    int je = off[node + 1];
    for (int j = jb; j < je; ++j) {
        int s = edge_src[j];                       // uniform broadcast load
        float e = ls[s] + ldv;
        e = (e >= 0.0f) ? e : NEG_SLOPE * e;
        float hv = h[s * 64 + lane];               // coalesced 256B row
        float p;
        if (e > m) {                                // wave-uniform branch
            float sc = __expf(m - e);
            acc *= sc;
            lsum *= sc;
            m = e;
            p = 1.0f;
        } else {
            p = __expf(e - m);
        }
        lsum += p;
        acc += p * hv;
    }
    float outv = acc / lsum + bias[lane];
    outv = (outv > 0.0f) ? outv : expm1f(outv);     // ELU (alpha=1)
    hout[node * 64 + lane] = outv;
}

// ---------------------------------------------------------------------------
// Global max pool: monotonic-unsigned encoding + atomicMax
// ---------------------------------------------------------------------------
__device__ __forceinline__ unsigned enc_f32(float f) {
    unsigned b = __float_as_uint(f);
    return (b & 0x80000000u) ? ~b : (b | 0x80000000u);
}

__global__ void pool_kernel(const float* __restrict__ h, const int* __restrict__ batch,
                            unsigned* __restrict__ genc, int n) {
    int idx = blockIdx.x * blockDim.x + threadIdx.x;
    int node = idx >> 6;
    int lane = idx & 63;
    if (node >= n) return;
    float v = h[node * 64 + lane];
    atomicMax(&genc[batch[node] * 64 + lane], enc_f32(v));
}

__global__ __launch_bounds__(64) void final_kernel(const unsigned* __restrict__ genc,
                                                   const float* __restrict__ linW,
                                                   const float* __restrict__ linb,
                                                   float* __restrict__ out) {
    int g = blockIdx.x;
    int lane = threadIdx.x;
    unsigned u = genc[g * 64 + lane];
    float v;
    if (u == 0u) {
        v = 0.0f;  // empty segment -> 0 (matches isfinite fixup)
    } else {
        unsigned b = (u & 0x80000000u) ? (u ^ 0x80000000u) : ~u;
        v = __uint_as_float(b);
    }
    float c0 = v * linW[lane * 2 + 0];
    float c1 = v * linW[lane * 2 + 1];
#pragma unroll
    for (int d = 32; d >= 1; d >>= 1) {
        c0 += __shfl_xor(c0, d, 64);
        c1 += __shfl_xor(c1, d, 64);
    }
    if (lane == 0) {
        out[g * 2 + 0] = c0 + linb[0];
        out[g * 2 + 1] = c1 + linb[1];
    }
}

// ---------------------------------------------------------------------------
// Launch
// ---------------------------------------------------------------------------
static inline size_t align_up(size_t v, size_t a) { return (v + a - 1) & ~(a - 1); }

extern "C" void kernel_launch(void* const* d_in, const int* in_sizes, int n_in,
                              void* d_out, int out_size, void* d_ws, size_t ws_size,
                              hipStream_t stream) {
    const float* x          = (const float*)d_in[0];
    const int*   edge_index = (const int*)d_in[1];
    const int*   batch      = (const int*)d_in[2];
    const float* W[5];
    const float* a_s[5];
    const float* a_d[5];
    const float* bias[5];
    for (int l = 0; l < 5; ++l) {
        W[l]    = (const float*)d_in[3 + 4 * l + 0];
        a_s[l]  = (const float*)d_in[3 + 4 * l + 1];
        a_d[l]  = (const float*)d_in[3 + 4 * l + 2];
        bias[l] = (const float*)d_in[3 + 4 * l + 3];
    }
    const float* linW = (const float*)d_in[23];
    const float* linb = (const float*)d_in[24];
    float* out = (float*)d_out;

    const int N = N_NODES;
    const int E = in_sizes[1] / 2;
    const int* srcp = edge_index;
    const int* dstp = edge_index + E;

    // workspace partition
    char* p = (char*)d_ws;
    int* counts = (int*)p;        p += align_up((size_t)N * 4, 256);
    int* off    = (int*)p;        p += align_up((size_t)(N + 1) * 4, 256);
    int* fill   = (int*)p;        p += align_up((size_t)N * 4, 256);
    int* esrc   = (int*)p;        p += align_up((size_t)E * 4, 256);
    float* lsb  = (float*)p;      p += align_up((size_t)N * 4, 256);
    float* ldb  = (float*)p;      p += align_up((size_t)N * 4, 256);
    float* h_a  = (float*)p;      p += align_up((size_t)N * 64 * 4, 256);
    float* h_b  = (float*)p;      p += align_up((size_t)N * 64 * 4, 256);
    unsigned* genc = (unsigned*)p; p += align_up((size_t)G_GRAPHS * 64 * 4, 256);

    hipMemsetAsync(counts, 0, (size_t)N * 4, stream);
    hipMemsetAsync(fill, 0, (size_t)N * 4, stream);
    hipMemsetAsync(genc, 0, (size_t)G_GRAPHS * 64 * 4, stream);

    int eb = (E + 255) / 256;
    hist_kernel<<<eb, 256, 0, stream>>>(dstp, counts, E);
    scan_kernel<<<1, 1024, 0, stream>>>(counts, off, N);
    scatter_kernel<<<eb, 256, 0, stream>>>(srcp, dstp, off, fill, esrc, E);

    int nb = (N + 3) / 4;
    // layer 0: x -> h_b -> h_a
    gemm_logits_kernel<14><<<nb, 256, 0, stream>>>(x, W[0], a_s[0], a_d[0],
                                                   h_b, lsb, ldb, N);
    gat_aggregate_kernel<<<nb, 256, 0, stream>>>(h_b, lsb, ldb, off, esrc,
                                                 bias[0], h_a, N);
    for (int l = 1; l < 5; ++l) {
        gemm_logits_kernel<64><<<nb, 256, 0, stream>>>(h_a, W[l], a_s[l], a_d[l],
                                                       h_b, lsb, ldb, N);
        gat_aggregate_kernel<<<nb, 256, 0, stream>>>(h_b, lsb, ldb, off, esrc,
                                                     bias[l], h_a, N);
    }

    int pb = (N * 64 + 255) / 256;
    pool_kernel<<<pb, 256, 0, stream>>>(h_a, batch, genc, N);
    final_kernel<<<G_GRAPHS, 64, 0, stream>>>(genc, linW, linb, out);
}

// Round 2
// 907.994 us; speedup vs baseline: 1.9470x; 1.9470x over previous
//
#include <hip/hip_runtime.h>
#include <math.h>

#define N_NODES 100000
#define H_DIM 64
#define G_GRAPHS 512
#define NEG_SLOPE 0.2f
#define SCAN_CHUNK 512

// ---------------------------------------------------------------------------
// CSR build
// ---------------------------------------------------------------------------
__global__ void hist_kernel(const int* __restrict__ dst, int* __restrict__ counts, int E) {
    int e = blockIdx.x * blockDim.x + threadIdx.x;
    if (e < E) atomicAdd(&counts[dst[e]], 1);
}

// pass 1: per-block partial sums over SCAN_CHUNK counts
__global__ __launch_bounds__(256) void scan_part_kernel(const int* __restrict__ counts,
                                                        int* __restrict__ part, int n) {
    __shared__ int sm[256];
    int b = blockIdx.x, t = threadIdx.x;
    int i = b * SCAN_CHUNK + t;
    int s = 0;
    if (i < n) s += counts[i];
    if (i + 256 < n && t + 256 < SCAN_CHUNK) s += counts[i + 256];
    sm[t] = s;
    __syncthreads();
    for (int d = 128; d >= 1; d >>= 1) {
        if (t < d) sm[t] += sm[t + d];
        __syncthreads();
    }
    if (t == 0) part[b] = sm[0];
}

// pass 2: exclusive scan of up to 256 block partials (B <= 256)
__global__ __launch_bounds__(256) void scan_top_kernel(const int* __restrict__ part,
                                                       int* __restrict__ partx,
                                                       int* __restrict__ off,
                                                       int B, int n) {
    __shared__ int sm[256];
    int t = threadIdx.x;
    sm[t] = (t < B) ? part[t] : 0;
    __syncthreads();
    for (int d = 1; d < 256; d <<= 1) {
        int v = (t >= d) ? sm[t - d] : 0;
        __syncthreads();
        sm[t] += v;
        __syncthreads();
    }
    if (t < B) partx[t] = (t == 0) ? 0 : sm[t - 1];
    if (t == 0) off[n] = sm[255];
}

// pass 3: per-block exclusive scan + add block base
__global__ __launch_bounds__(256) void scan_down_kernel(const int* __restrict__ counts,
                                                        const int* __restrict__ partx,
                                                        int* __restrict__ off, int n) {
    __shared__ int sm[256];
    int b = blockIdx.x, t = threadIdx.x;
    int i0 = b * SCAN_CHUNK + 2 * t;
    int c0 = (i0 < n) ? counts[i0] : 0;
    int c1 = (i0 + 1 < n) ? counts[i0 + 1] : 0;
    sm[t] = c0 + c1;
    __syncthreads();
    for (int d = 1; d < 256; d <<= 1) {
        int v = (t >= d) ? sm[t - d] : 0;
        __syncthreads();
        sm[t] += v;
        __syncthreads();
    }
    int base = partx[b] + ((t == 0) ? 0 : sm[t - 1]);
    if (i0 < n) off[i0] = base;
    if (i0 + 1 < n) off[i0 + 1] = base + c0;
}

__global__ void scatter_kernel(const int* __restrict__ src, const int* __restrict__ dst,
                               const int* __restrict__ off, int* __restrict__ fill,
                               int* __restrict__ edge_src, int E) {
    int e = blockIdx.x * blockDim.x + threadIdx.x;
    if (e < E) {
        int d = dst[e];
        int pos = off[d] + atomicAdd(&fill[d], 1);
        edge_src[pos] = src[e];
    }
}

// ---------------------------------------------------------------------------
// Fused GEMM + attention logits: h = act @ W ; ls = h.a_s ; ld = h.a_d
// W column in VGPRs (lane = output feature); x row via wave-uniform loads.
// ---------------------------------------------------------------------------
template <int FIN>
__global__ __launch_bounds__(256) void gemm_logits_kernel(
        const float* __restrict__ act, const float* __restrict__ W,
        const float* __restrict__ a_s, const float* __restrict__ a_d,
        float* __restrict__ h, float* __restrict__ ls, float* __restrict__ ld,
        int n) {
    int lane = threadIdx.x & 63;
    float Wc[FIN];
#pragma unroll
    for (int k = 0; k < FIN; ++k) Wc[k] = W[k * 64 + lane];   // coalesced
    float asv = a_s[lane];
    float adv = a_d[lane];

    int nw = gridDim.x * 4;
    int wid = blockIdx.x * 4 + (threadIdx.x >> 6);
    for (int node = wid; node < n; node += nw) {
        const float* xr = act + (size_t)node * FIN;   // wave-uniform address
        float a0 = 0.0f, a1 = 0.0f, a2 = 0.0f, a3 = 0.0f;
#pragma unroll
        for (int k = 0; k + 4 <= FIN; k += 4) {
            a0 = fmaf(xr[k + 0], Wc[k + 0], a0);
            a1 = fmaf(xr[k + 1], Wc[k + 1], a1);
            a2 = fmaf(xr[k + 2], Wc[k + 2], a2);
            a3 = fmaf(xr[k + 3], Wc[k + 3], a3);
        }
#pragma unroll
        for (int k = FIN & ~3; k < FIN; ++k) a0 = fmaf(xr[k], Wc[k], a0);
        float acc = (a0 + a1) + (a2 + a3);
        float vs = acc * asv;
        float vd = acc * adv;
#pragma unroll
        for (int d = 32; d >= 1; d >>= 1) {
            vs += __shfl_xor(vs, d, 64);
            vd += __shfl_xor(vd, d, 64);
        }
        h[(size_t)node * 64 + lane] = acc;
        if (lane == 0) { ls[node] = vs; ld[node] = vd; }
    }
}

// ---------------------------------------------------------------------------
// GAT aggregation. One wave per node. Phase A: lanes parallel over edges
// (logit, wave-max, exp, wave-sum). Phase B: 16-lane groups x 4 edges/iter,
// float4 row gathers. Two-pass for the rare deg>64 node.
// ---------------------------------------------------------------------------
__global__ __launch_bounds__(256) void gat_aggregate_kernel(
        const float* __restrict__ h, const float* __restrict__ ls,
        const float* __restrict__ ld, const int* __restrict__ off,
        const int* __restrict__ esrc, const float* __restrict__ bias,
        float* __restrict__ hout, int n) {
    int t = threadIdx.x;
    int lane = t & 63;
    int node = blockIdx.x * 4 + (t >> 6);
    if (node >= n) return;
    int grp = lane >> 4;
    int fl = lane & 15;

    int jb = off[node];
    int je = off[node + 1];
    int deg = je - jb;
    float ldv = ld[node];
    float e0 = ls[node] + ldv;
    e0 = (e0 >= 0.0f) ? e0 : NEG_SLOPE * e0;

    float4 acc = make_float4(0.0f, 0.0f, 0.0f, 0.0f);
    float denp = 0.0f;
    float m;

    if (deg <= 64) {
        int j = jb + lane;
        bool v = j < je;
        int s = v ? esrc[j] : 0;
        float e = -1e30f;
        if (v) {
            e = ls[s] + ldv;
            e = (e >= 0.0f) ? e : NEG_SLOPE * e;
        }
        float mm = fmaxf(e0, e);
#pragma unroll
        for (int d = 32; d >= 1; d >>= 1) mm = fmaxf(mm, __shfl_xor(mm, d, 64));
        m = mm;
        float p = v ? __expf(e - m) : 0.0f;
        denp = p;
        int cnt4 = (deg + 3) & ~3;
        for (int tt = 0; tt < cnt4; tt += 4) {
            int   si = __shfl(s, tt + grp, 64);
            float pi = __shfl(p, tt + grp, 64);
            const float4 hv = *(const float4*)(h + (size_t)si * 64 + fl * 4);
            acc.x = fmaf(pi, hv.x, acc.x);
            acc.y = fmaf(pi, hv.y, acc.y);
            acc.z = fmaf(pi, hv.z, acc.z);
            acc.w = fmaf(pi, hv.w, acc.w);
        }
    } else {
        float mm = e0;
        for (int base = jb; base < je; base += 64) {
            int j = base + lane;
            if (j < je) {
                int s = esrc[j];
                float e = ls[s] + ldv;
                e = (e >= 0.0f) ? e : NEG_SLOPE * e;
                mm = fmaxf(mm, e);
            }
        }
#pragma unroll
        for (int d = 32; d >= 1; d >>= 1) mm = fmaxf(mm, __shfl_xor(mm, d, 64));
        m = mm;
        for (int base = jb; base < je; base += 64) {
            int j = base + lane;
            bool v = j < je;
            int s = v ? esrc[j] : 0;
            float p = 0.0f;
            if (v) {
                float e = ls[s] + ldv;
                e = (e >= 0.0f) ? e : NEG_SLOPE * e;
                p = __expf(e - m);
            }
            denp += p;
            int cnt = je - base; if (cnt > 64) cnt = 64;
            int cnt4 = (cnt + 3) & ~3;
            for (int tt = 0; tt < cnt4; tt += 4) {
                int   si = __shfl(s, tt + grp, 64);
                float pi = __shfl(p, tt + grp, 64);
                const float4 hv = *(const float4*)(h + (size_t)si * 64 + fl * 4);
                acc.x = fmaf(pi, hv.x, acc.x);
                acc.y = fmaf(pi, hv.y, acc.y);
                acc.z = fmaf(pi, hv.z, acc.z);
                acc.w = fmaf(pi, hv.w, acc.w);
            }
        }
    }
#pragma unroll
    for (int d = 32; d >= 1; d >>= 1) denp += __shfl_xor(denp, d, 64);
    float p0 = __expf(e0 - m);
    float den = denp + p0;
    // combine the 4 groups (disjoint edge subsets, same feature slice fl)
    acc.x += __shfl_xor(acc.x, 16, 64); acc.y += __shfl_xor(acc.y, 16, 64);
    acc.z += __shfl_xor(acc.z, 16, 64); acc.w += __shfl_xor(acc.w, 16, 64);
    acc.x += __shfl_xor(acc.x, 32, 64); acc.y += __shfl_xor(acc.y, 32, 64);
    acc.z += __shfl_xor(acc.z, 32, 64); acc.w += __shfl_xor(acc.w, 32, 64);

    const float4 hs = *(const float4*)(h + (size_t)node * 64 + fl * 4);
    acc.x = fmaf(p0, hs.x, acc.x);
    acc.y = fmaf(p0, hs.y, acc.y);
    acc.z = fmaf(p0, hs.z, acc.z);
    acc.w = fmaf(p0, hs.w, acc.w);

    const float4 b4 = *(const float4*)(bias + fl * 4);
    float inv = 1.0f / den;
    float4 o;
    o.x = acc.x * inv + b4.x;
    o.y = acc.y * inv + b4.y;
    o.z = acc.z * inv + b4.z;
    o.w = acc.w * inv + b4.w;
    o.x = (o.x > 0.0f) ? o.x : expm1f(o.x);
    o.y = (o.y > 0.0f) ? o.y : expm1f(o.y);
    o.z = (o.z > 0.0f) ? o.z : expm1f(o.z);
    o.w = (o.w > 0.0f) ? o.w : expm1f(o.w);
    if (grp == 0) *(float4*)(hout + (size_t)node * 64 + fl * 4) = o;
}

// ---------------------------------------------------------------------------
// Global max pool: run-length (batch is sorted) + encoded atomicMax
// ---------------------------------------------------------------------------
__device__ __forceinline__ unsigned enc_f32(float f) {
    unsigned b = __float_as_uint(f);
    return (b & 0x80000000u) ? ~b : (b | 0x80000000u);
}

__global__ __launch_bounds__(256) void pool_kernel(const float* __restrict__ h,
                                                   const int* __restrict__ batch,
                                                   unsigned* __restrict__ genc, int n) {
    int lane = threadIdx.x & 63;
    int w = blockIdx.x * 4 + (threadIdx.x >> 6);
    int start = w * 64;
    if (start >= n) return;
    int end = start + 64; if (end > n) end = n;
    int cur = batch[start];
    float rm = -1e38f;
    for (int node = start; node < end; ++node) {
        int b = batch[node];                     // wave-uniform
        if (b != cur) {
            atomicMax(&genc[cur * 64 + lane], enc_f32(rm));
            cur = b;
            rm = -1e38f;
        }
        rm = fmaxf(rm, h[(size_t)node * 64 + lane]);
    }
    atomicMax(&genc[cur * 64 + lane], enc_f32(rm));
}

__global__ __launch_bounds__(64) void final_kernel(const unsigned* __restrict__ genc,
                                                   const float* __restrict__ linW,
                                                   const float* __restrict__ linb,
                                                   float* __restrict__ out) {
    int g = blockIdx.x;
    int lane = threadIdx.x;
    unsigned u = genc[g * 64 + lane];
    float v;
    if (u == 0u) {
        v = 0.0f;
    } else {
        unsigned b = (u & 0x80000000u) ? (u ^ 0x80000000u) : ~u;
        v = __uint_as_float(b);
    }
    float c0 = v * linW[lane * 2 + 0];
    float c1 = v * linW[lane * 2 + 1];
#pragma unroll
    for (int d = 32; d >= 1; d >>= 1) {
        c0 += __shfl_xor(c0, d, 64);
        c1 += __shfl_xor(c1, d, 64);
    }
    if (lane == 0) {
        out[g * 2 + 0] = c0 + linb[0];
        out[g * 2 + 1] = c1 + linb[1];
    }
}

// ---------------------------------------------------------------------------
// Launch
// ---------------------------------------------------------------------------
static inline size_t align_up(size_t v, size_t a) { return (v + a - 1) & ~(a - 1); }

extern "C" void kernel_launch(void* const* d_in, const int* in_sizes, int n_in,
                              void* d_out, int out_size, void* d_ws, size_t ws_size,
                              hipStream_t stream) {
    const float* x          = (const float*)d_in[0];
    const int*   edge_index = (const int*)d_in[1];
    const int*   batch      = (const int*)d_in[2];
    const float* W[5];
    const float* a_s[5];
    const float* a_d[5];
    const float* bias[5];
    for (int l = 0; l < 5; ++l) {
        W[l]    = (const float*)d_in[3 + 4 * l + 0];
        a_s[l]  = (const float*)d_in[3 + 4 * l + 1];
        a_d[l]  = (const float*)d_in[3 + 4 * l + 2];
        bias[l] = (const float*)d_in[3 + 4 * l + 3];
    }
    const float* linW = (const float*)d_in[23];
    const float* linb = (const float*)d_in[24];
    float* out = (float*)d_out;

    const int N = N_NODES;
    const int E = in_sizes[1] / 2;
    const int* srcp = edge_index;
    const int* dstp = edge_index + E;
    const int B = (N + SCAN_CHUNK - 1) / SCAN_CHUNK;   // 196 <= 256

    // workspace partition (counts+fill adjacent -> one memset)
    char* p = (char*)d_ws;
    int* counts = (int*)p;        p += align_up((size_t)N * 4, 256);
    int* fill   = (int*)p;        p += align_up((size_t)N * 4, 256);
    int* off    = (int*)p;        p += align_up((size_t)(N + 1) * 4, 256);
    int* part   = (int*)p;        p += align_up((size_t)B * 4, 256);
    int* partx  = (int*)p;        p += align_up((size_t)B * 4, 256);
    int* esrc   = (int*)p;        p += align_up((size_t)E * 4, 256);
    float* lsb  = (float*)p;      p += align_up((size_t)N * 4, 256);
    float* ldb  = (float*)p;      p += align_up((size_t)N * 4, 256);
    float* h_a  = (float*)p;      p += align_up((size_t)N * 64 * 4, 256);
    float* h_b  = (float*)p;      p += align_up((size_t)N * 64 * 4, 256);
    unsigned* genc = (unsigned*)p; p += align_up((size_t)G_GRAPHS * 64 * 4, 256);

    hipMemsetAsync(counts, 0, align_up((size_t)N * 4, 256) + (size_t)N * 4, stream);
    hipMemsetAsync(genc, 0, (size_t)G_GRAPHS * 64 * 4, stream);

    int eb = (E + 255) / 256;
    hist_kernel<<<eb, 256, 0, stream>>>(dstp, counts, E);
    scan_part_kernel<<<B, 256, 0, stream>>>(counts, part, N);
    scan_top_kernel<<<1, 256, 0, stream>>>(part, partx, off, B, N);
    scan_down_kernel<<<B, 256, 0, stream>>>(counts, partx, off, N);
    scatter_kernel<<<eb, 256, 0, stream>>>(srcp, dstp, off, fill, esrc, E);

    int nb = (N + 3) / 4;
    int gb = 2048;   // GEMM: grid-stride waves, W held in VGPRs
    gemm_logits_kernel<14><<<gb, 256, 0, stream>>>(x, W[0], a_s[0], a_d[0],
                                                   h_b, lsb, ldb, N);
    gat_aggregate_kernel<<<nb, 256, 0, stream>>>(h_b, lsb, ldb, off, esrc,
                                                 bias[0], h_a, N);
    for (int l = 1; l < 5; ++l) {
        gemm_logits_kernel<64><<<gb, 256, 0, stream>>>(h_a, W[l], a_s[l], a_d[l],
                                                       h_b, lsb, ldb, N);
        gat_aggregate_kernel<<<nb, 256, 0, stream>>>(h_b, lsb, ldb, off, esrc,
                                                     bias[l], h_a, N);
    }

    int pw = (N + 63) / 64;
    int pb = (pw + 3) / 4;
    pool_kernel<<<pb, 256, 0, stream>>>(h_a, batch, genc, N);
    final_kernel<<<G_GRAPHS, 64, 0, stream>>>(genc, linW, linb, out);
}